// Round 2
// baseline (50.763 us; speedup 1.0000x reference)
//
#include <hip/hip_runtime.h>
#include <hip/hip_bf16.h>

#define HH 512
#define WW 512
#define HWSZ (512*512)

typedef _Float16 hh4 __attribute__((ext_vector_type(4)));

__device__ __forceinline__ float clamp01(float x) {
    return __builtin_amdgcn_fmed3f(x, 0.0f, 1.0f);
}

__global__ __launch_bounds__(256, 2)
void mlr_kernel(const float* __restrict__ rgbad,
                const float* __restrict__ lens_eff,
                const float* __restrict__ focal,
                float* __restrict__ out)
{
    constexpr int TW = 64, TH = 16;
    constexpr int SW = TW + 20;   // 84 source cols
    constexpr int SH = TH + 20;   // 36 source rows
    constexpr int LP = SW + 1;    // 85: odd stride (bank-friendly)

    __shared__ uint2 sL[SH * LP];   // premultiplied (r,g,b,a)/area as half4
    __shared__ float rL[SH * LP];   // rp05 = clip(|disp|*lens,0,10)+0.5 (0 in pad)
    __shared__ int   maxbits;

    const int tx  = threadIdx.x;           // 0..15
    const int ty  = threadIdx.y;           // 0..15
    const int tid = ty * 16 + tx;
    const int bx0 = blockIdx.x * TW;
    const int by0 = blockIdx.y * TH;
    const int bb  = blockIdx.z;
    const float lens = lens_eff[bb];

    // distinct squared distances v=dy^2+dx^2<=100 in the masked 21x21 footprint,
    // DJ=sqrt(v), CNT=multiplicity (sum of CNT = 317 masked taps)
    static constexpr float DJ[44] = {
        0.f, 1.f, 1.41421356f, 2.f, 2.23606798f, 2.82842712f, 3.f, 3.16227766f,
        3.60555128f, 4.f, 4.12310563f, 4.24264069f, 4.47213595f, 5.f, 5.09901951f,
        5.38516481f, 5.65685425f, 5.83095189f, 6.f, 6.08276253f, 6.32455532f,
        6.40312424f, 6.70820393f, 7.f, 7.07106781f, 7.21110255f, 7.28010989f,
        7.61577311f, 7.81024968f, 8.f, 8.06225775f, 8.24621125f, 8.48528137f,
        8.54400375f, 8.60232527f, 8.94427191f, 9.f, 9.05538514f, 9.21954446f,
        9.43398113f, 9.48683298f, 9.84885780f, 9.89949494f, 10.f };
    static constexpr float CNT[44] = {
        1,4,4,4,8,4,4,8,8,4,8,4,8,12,8,8,4,8,4,8,8,8,
        8,4,12,8,8,8,8,4,16,8,4,8,8,8,4,8,16,8,8,8,4,12 };

    float blurR[4] = {0,0,0,0}, blurG[4] = {0,0,0,0}, blurB[4] = {0,0,0,0};
    float trans[4] = {1,1,1,1};

#pragma unroll 1
    for (int l = 0; l < 3; ++l) {
        __syncthreads();                 // previous layer's gather done
        if (tid == 0) maxbits = 0;
        __syncthreads();                 // reset visible

        const float* pin = rgbad + (size_t)(bb * 15 + 5 * l) * HWSZ;
        const float* pfo = focal + (size_t)(bb * 15 + 5 * l) * HWSZ;
        float mloc = 0.f;
#pragma unroll 1
        for (int i = tid; i < SH * SW; i += 256) {
            const int row = i / SW;
            const int col = i - row * SW;
            const int gy = by0 - 10 + row;
            const int gx = bx0 - 10 + col;
            uint2 pk; pk.x = 0u; pk.y = 0u;
            float rp05 = 0.f;
            if ((unsigned)gy < (unsigned)HH && (unsigned)gx < (unsigned)WW) {
                const int off = gy * WW + gx;
                const float cr = pin[off]            - pfo[off];
                const float cg = pin[off +   HWSZ]   - pfo[off +   HWSZ];
                const float cb = pin[off + 2*HWSZ]   - pfo[off + 2*HWSZ];
                const float ca = pin[off + 3*HWSZ]   - pfo[off + 3*HWSZ];
                const float cd = pin[off + 4*HWSZ]   - pfo[off + 4*HWSZ];
                const float r  = fminf(fabsf(cd) * lens, 10.f);
                rp05 = r + 0.5f;
                float a0 = 0.f, a1 = 0.f;
#pragma unroll
                for (int j = 0; j < 44; j += 2) {
                    a0 = fmaf(CNT[j],     clamp01(rp05 - DJ[j]),     a0);
                    a1 = fmaf(CNT[j + 1], clamp01(rp05 - DJ[j + 1]), a1);
                }
                const float inv = 1.0f / (a0 + a1 + 1e-8f);
                const float pa  = ca * inv;
                hh4 hv;
                hv.x = (_Float16)(cr * pa);
                hv.y = (_Float16)(cg * pa);
                hv.z = (_Float16)(cb * pa);
                hv.w = (_Float16)pa;
                pk = __builtin_bit_cast(uint2, hv);
                mloc = fmaxf(mloc, rp05);
            }
            sL[row * LP + col] = pk;
            rL[row * LP + col] = rp05;
        }
        atomicMax(&maxbits, __float_as_int(mloc));   // positive floats: int max ok
        __syncthreads();

        const float rmax = __int_as_float(maxbits);
        const int U = min(10, (int)ceilf(rmax) - 1);  // rows |u|<=U can contribute

        float accR[4] = {0,0,0,0}, accG[4] = {0,0,0,0};
        float accB[4] = {0,0,0,0}, accW[4] = {0,0,0,0};

#pragma unroll 1
        for (int u = -U; u <= U; ++u) {
            const float u2f = (float)(u * u);
            float dd[21];                 // dist for dx=-10..10 (1e9 outside disk)
#pragma unroll
            for (int k = 0; k < 21; ++k) {
                const int dxk = k - 10;
                const float q = u2f + (float)(dxk * dxk);
                dd[k] = (q <= 100.0f) ? __builtin_sqrtf(q) : 1e9f;
            }
            const int rbase = (ty + 10 + u) * LP + 10 + 4 * tx;
#pragma unroll
            for (int v = -10; v <= 13; ++v) {
                const float rp = rL[rbase + v];
                const uint2 sp = sL[rbase + v];
                const hh4 hv = __builtin_bit_cast(hh4, sp);
                const float s0 = (float)hv.x;
                const float s1 = (float)hv.y;
                const float s2 = (float)hv.z;
                const float s3 = (float)hv.w;
#pragma unroll
                for (int ox = 0; ox < 4; ++ox) {
                    const int dx = v - ox;               // compile-time per (v,ox)
                    if (dx >= -10 && dx <= 10) {
                        const float w = clamp01(rp - dd[dx + 10]);
                        accR[ox] = fmaf(s0, w, accR[ox]);
                        accG[ox] = fmaf(s1, w, accG[ox]);
                        accB[ox] = fmaf(s2, w, accB[ox]);
                        accW[ox] = fmaf(s3, w, accW[ox]);
                    }
                }
            }
        }

        // front-to-back compositing (uniform formula; trans=1 at l=0)
#pragma unroll
        for (int ox = 0; ox < 4; ++ox) {
            const float wsum = accW[ox];
            const float occ  = clamp01(wsum);
            const float f    = trans[ox] * occ / (wsum + 1e-8f);
            blurR[ox] = fmaf(accR[ox], f, blurR[ox]);
            blurG[ox] = fmaf(accG[ox], f, blurG[ox]);
            blurB[ox] = fmaf(accB[ox], f, blurB[ox]);
            trans[ox] *= (1.0f - occ);
        }
    }

    const int oy = by0 + ty;
    const size_t obase = (size_t)bb * 3 * HWSZ + (size_t)oy * WW + (size_t)(bx0 + 4 * tx);

    float4 vR, vG, vB;
    vR.x = blurR[0]; vR.y = blurR[1]; vR.z = blurR[2]; vR.w = blurR[3];
    vG.x = blurG[0]; vG.y = blurG[1]; vG.z = blurG[2]; vG.w = blurG[3];
    vB.x = blurB[0]; vB.y = blurB[1]; vB.z = blurB[2]; vB.w = blurB[3];

    *reinterpret_cast<float4*>(out + obase)            = vR;
    *reinterpret_cast<float4*>(out + obase + HWSZ)     = vG;
    *reinterpret_cast<float4*>(out + obase + 2 * HWSZ) = vB;
}

extern "C" void kernel_launch(void* const* d_in, const int* in_sizes, int n_in,
                              void* d_out, int out_size, void* d_ws, size_t ws_size,
                              hipStream_t stream) {
    const float* rgbad = (const float*)d_in[0];
    const float* lens  = (const float*)d_in[1];
    const float* focal = (const float*)d_in[2];
    float* out = (float*)d_out;
    const int B = in_sizes[1];                 // lens_effect: [B,1]
    dim3 grid(WW / 64, HH / 16, B);
    dim3 block(16, 16, 1);
    hipLaunchKernelGGL(mlr_kernel, grid, block, 0, stream, rgbad, lens, focal, out);
}